// Round 2
// baseline (418.003 us; speedup 1.0000x reference)
//
#include <hip/hip_runtime.h>
#include <hip/hip_bf16.h>

#define N_NODES 50000
#define N_EDGES 800000
#define IN_FEAT 256
#define UNITS   128

// ---------------------------------------------------------------------------
// K1: h = node_states(50000x256) @ kernel(256x128), fp32 vector GEMM.
// BM=64 rows/block, full N=128, BK=32. 256 threads, 4x8 micro-tile.
// ---------------------------------------------------------------------------
__global__ __launch_bounds__(256) void gemm_h(const float* __restrict__ A,
                                              const float* __restrict__ W,
                                              float* __restrict__ H, int M) {
    __shared__ float As[64][33];   // +1 pad
    __shared__ float Ws[32][128];
    const int tid = threadIdx.x;
    const int tx = tid & 15;
    const int ty = tid >> 4;
    const int row0 = blockIdx.x * 64;

    float acc[4][8];
#pragma unroll
    for (int i = 0; i < 4; ++i)
#pragma unroll
        for (int j = 0; j < 8; ++j) acc[i][j] = 0.f;

    for (int kc = 0; kc < IN_FEAT; kc += 32) {
        // A tile: 64x32 = 2048 floats, 8/thread (2x float4)
        {
            int flat = tid * 8;
            int r = flat >> 5;
            int c = flat & 31;
            int gr = row0 + r;
            gr = gr < M ? gr : M - 1;           // clamp; OOB rows never stored
            const float4* p = (const float4*)(A + (size_t)gr * IN_FEAT + kc + c);
            float4 v0 = p[0];
            float4 v1 = p[1];
            As[r][c + 0] = v0.x; As[r][c + 1] = v0.y; As[r][c + 2] = v0.z; As[r][c + 3] = v0.w;
            As[r][c + 4] = v1.x; As[r][c + 5] = v1.y; As[r][c + 6] = v1.z; As[r][c + 7] = v1.w;
        }
        // W tile: 32x128 = 4096 floats, 16/thread (4x float4)
        {
            int flat = tid * 16;
            int r = flat >> 7;
            int c = flat & 127;
            const float4* p = (const float4*)(W + (size_t)(kc + r) * UNITS + c);
            float4 v0 = p[0], v1 = p[1], v2 = p[2], v3 = p[3];
            *(float4*)&Ws[r][c + 0]  = v0;
            *(float4*)&Ws[r][c + 4]  = v1;
            *(float4*)&Ws[r][c + 8]  = v2;
            *(float4*)&Ws[r][c + 12] = v3;
        }
        __syncthreads();
#pragma unroll
        for (int kk = 0; kk < 32; ++kk) {
            float a0 = As[ty * 4 + 0][kk];
            float a1 = As[ty * 4 + 1][kk];
            float a2 = As[ty * 4 + 2][kk];
            float a3 = As[ty * 4 + 3][kk];
            float b[8];
#pragma unroll
            for (int j = 0; j < 8; ++j) b[j] = Ws[kk][tx + 16 * j];
#pragma unroll
            for (int j = 0; j < 8; ++j) {
                acc[0][j] += a0 * b[j];
                acc[1][j] += a1 * b[j];
                acc[2][j] += a2 * b[j];
                acc[3][j] += a3 * b[j];
            }
        }
        __syncthreads();
    }
#pragma unroll
    for (int i = 0; i < 4; ++i) {
        int gr = row0 + ty * 4 + i;
        if (gr < M) {
#pragma unroll
            for (int j = 0; j < 8; ++j)
                H[(size_t)gr * UNITS + tx + 16 * j] = acc[i][j];
        }
    }
}

// ---------------------------------------------------------------------------
// K1b: per-node attention logits. One wave per node.
// ---------------------------------------------------------------------------
__global__ __launch_bounds__(256) void attn_dots(const float* __restrict__ H,
                                                 const float* __restrict__ ka,
                                                 float* __restrict__ a_tgt,
                                                 float* __restrict__ a_src, int M) {
    int wid  = (int)((blockIdx.x * 256 + threadIdx.x) >> 6);
    int lane = threadIdx.x & 63;
    if (wid >= M) return;
    float2 hv = *(const float2*)(H + (size_t)wid * UNITS + lane * 2);
    float2 kt = *(const float2*)(ka + lane * 2);
    float2 ks = *(const float2*)(ka + UNITS + lane * 2);
    float pt = hv.x * kt.x + hv.y * kt.y;
    float ps = hv.x * ks.x + hv.y * ks.y;
#pragma unroll
    for (int off = 32; off > 0; off >>= 1) {
        pt += __shfl_down(pt, off);
        ps += __shfl_down(ps, off);
    }
    if (lane == 0) { a_tgt[wid] = pt; a_src[wid] = ps; }
}

__device__ __forceinline__ float edge_score(float at, float as) {
    float s = at + as;
    s = s > 0.f ? s : 0.2f * s;          // leaky_relu
    s = fminf(fmaxf(s, -2.f), 2.f);      // clip
    return __expf(s);
}

// ---------------------------------------------------------------------------
// K2: per-edge score -> denom (fp32 atomic) + degree histogram (int atomic)
// ---------------------------------------------------------------------------
__global__ __launch_bounds__(256) void edge_scores(const int* __restrict__ edges,
                                                   const float* __restrict__ at,
                                                   const float* __restrict__ as,
                                                   float* __restrict__ denom,
                                                   int* __restrict__ counts, int E) {
    int e = blockIdx.x * 256 + threadIdx.x;
    if (e >= E) return;
    int2 ts = ((const int2*)edges)[e];   // (tgt, src)
    float sc = edge_score(at[ts.x], as[ts.y]);
    atomicAdd(&denom[ts.x], sc);
    atomicAdd(&counts[ts.x], 1);
}

// ---------------------------------------------------------------------------
// K3: single-block exclusive scan counts[0..n) -> offsets[0..n]
// ---------------------------------------------------------------------------
__global__ __launch_bounds__(1024) void scan_offsets(const int* __restrict__ counts,
                                                     int* __restrict__ offsets, int n) {
    const int tid = threadIdx.x;
    const int PER = (n + 1023) / 1024;
    int start = tid * PER;
    int end   = min(start + PER, n);

    int s = 0;
    for (int i = start; i < end; ++i) s += counts[i];

    __shared__ int wsum[16];
    int lane = tid & 63, wid = tid >> 6;
    int incl = s;
#pragma unroll
    for (int off = 1; off < 64; off <<= 1) {
        int t = __shfl_up(incl, off);
        if (lane >= off) incl += t;
    }
    if (lane == 63) wsum[wid] = incl;
    __syncthreads();
    if (tid == 0) {
        int run = 0;
        for (int i = 0; i < 16; ++i) { int v = wsum[i]; wsum[i] = run; run += v; }
    }
    __syncthreads();
    int run = wsum[wid] + (incl - s);    // exclusive base for this thread
    for (int i = start; i < end; ++i) { offsets[i] = run; run += counts[i]; }
    if (start < n && end == n) offsets[n] = run;   // owner of last element
}

// ---------------------------------------------------------------------------
// K4: scatter edges into CSR slots; weight = score / denom[tgt]
// ---------------------------------------------------------------------------
__global__ __launch_bounds__(256) void build_csr(const int* __restrict__ edges,
                                                 const float* __restrict__ at,
                                                 const float* __restrict__ as,
                                                 const float* __restrict__ denom,
                                                 const int* __restrict__ offsets,
                                                 int* __restrict__ cursor,
                                                 int* __restrict__ csr_src,
                                                 float* __restrict__ csr_w, int E) {
    int e = blockIdx.x * 256 + threadIdx.x;
    if (e >= E) return;
    int2 ts = ((const int2*)edges)[e];
    float sc = edge_score(at[ts.x], as[ts.y]);
    int pos = offsets[ts.x] + atomicAdd(&cursor[ts.x], 1);
    csr_src[pos] = ts.y;
    csr_w[pos]   = sc / denom[ts.x];
}

// ---------------------------------------------------------------------------
// K5: one wave per target node; lane covers 2 feature cols.
// Coalesced 512B gathers of h[src]; (src,w) broadcast via shfl.
// ---------------------------------------------------------------------------
__global__ __launch_bounds__(256) void aggregate(const float* __restrict__ H,
                                                 const int* __restrict__ offsets,
                                                 const int* __restrict__ csr_src,
                                                 const float* __restrict__ csr_w,
                                                 float* __restrict__ out, int M) {
    int wid  = (int)((blockIdx.x * 256 + threadIdx.x) >> 6);
    int lane = threadIdx.x & 63;
    if (wid >= M) return;
    int beg = offsets[wid];
    int end = offsets[wid + 1];
    float2 acc = make_float2(0.f, 0.f);
    for (int base = beg; base < end; base += 64) {
        int cd = min(64, end - base);
        int s_v = 0; float w_v = 0.f;
        if (lane < cd) { s_v = csr_src[base + lane]; w_v = csr_w[base + lane]; }
        for (int j = 0; j < cd; ++j) {
            int   src = __shfl(s_v, j);
            float w   = __shfl(w_v, j);
            float2 hv = *(const float2*)(H + (size_t)src * UNITS + lane * 2);
            acc.x += w * hv.x;
            acc.y += w * hv.y;
        }
    }
    *(float2*)(out + (size_t)wid * UNITS + lane * 2) = acc;
}

// ---------------------------------------------------------------------------
extern "C" void kernel_launch(void* const* d_in, const int* in_sizes, int n_in,
                              void* d_out, int out_size, void* d_ws, size_t ws_size,
                              hipStream_t stream) {
    const float* node_states = (const float*)d_in[0];
    const int*   edges       = (const int*)d_in[1];   // int32 pairs (tgt,src)
    const float* W           = (const float*)d_in[2];
    const float* ka          = (const float*)d_in[3];
    float*       out         = (float*)d_out;

    const int M = N_NODES, E = N_EDGES;

    // workspace layout (all 4B elems). NOTE: no trailing backslashes in
    // comments -- a trailing '\' line-splices the next line into the comment.
    float* h       = (float*)d_ws;                     // M*128
    float* a_tgt   = h + (size_t)M * UNITS;            // M
    float* a_src   = a_tgt + M;                        // M
    float* denom   = a_src + M;                        // M  -- zeroed
    int*   counts  = (int*)(denom + M);                // M  -- zeroed
    int*   cursor  = counts + M;                       // M  -- zeroed
    int*   offsets = cursor + M;                       // M+1
    int*   csr_src = offsets + M + 1;                  // E
    float* csr_w   = (float*)(csr_src + E);            // E
    // total ~33.2 MB

    (void)hipMemsetAsync(denom, 0, (size_t)M * 3 * sizeof(int), stream);

    gemm_h      <<<(M + 63) / 64, 256, 0, stream>>>(node_states, W, h, M);
    attn_dots   <<<(M * 64 + 255) / 256, 256, 0, stream>>>(h, ka, a_tgt, a_src, M);
    edge_scores <<<(E + 255) / 256, 256, 0, stream>>>(edges, a_tgt, a_src, denom, counts, E);
    scan_offsets<<<1, 1024, 0, stream>>>(counts, offsets, M);
    build_csr   <<<(E + 255) / 256, 256, 0, stream>>>(edges, a_tgt, a_src, denom, offsets,
                                                      cursor, csr_src, csr_w, E);
    aggregate   <<<(M * 64 + 255) / 256, 256, 0, stream>>>(h, offsets, csr_src, csr_w, out, M);
}

// Round 3
// 329.097 us; speedup vs baseline: 1.2702x; 1.2702x over previous
//
#include <hip/hip_runtime.h>
#include <hip/hip_bf16.h>

#define N_NODES 50000
#define N_EDGES 800000
#define IN_FEAT 256
#define UNITS   128

typedef unsigned short ushort_t;
typedef __bf16 bf16x8 __attribute__((ext_vector_type(8)));
typedef float  f32x4  __attribute__((ext_vector_type(4)));
typedef unsigned short ushort8 __attribute__((ext_vector_type(8)));

__device__ __forceinline__ ushort_t f2bf(float f) {
    unsigned u = __float_as_uint(f);
    u += 0x7fff + ((u >> 16) & 1);      // round-to-nearest-even
    return (ushort_t)(u >> 16);
}

// ---------------------------------------------------------------------------
// K0: Wt[n][k] = bf16(W[k][n])  (128 x 256 bf16, 64 KB) -- done once, tiny.
// ---------------------------------------------------------------------------
__global__ __launch_bounds__(256) void prep_wt(const float* __restrict__ W,
                                               ushort_t* __restrict__ Wt) {
    int i = blockIdx.x * 256 + threadIdx.x;     // i = n*256 + k
    if (i >= UNITS * IN_FEAT) return;
    int n = i >> 8;
    int k = i & 255;
    Wt[i] = f2bf(W[(size_t)k * UNITS + n]);
}

// ---------------------------------------------------------------------------
// K1: h = A(50000x256 fp32, cvt->bf16) @ W via MFMA 16x16x32 bf16.
// BM=64, BN=128(full), BK=32. 256 thr = 4 waves in 2x2; wave tile 32x64.
// LDS row stride 40 bf16 (80B = 20 banks -> 2-way conflicts only, free).
// ---------------------------------------------------------------------------
__global__ __launch_bounds__(256) void gemm_mfma(const float* __restrict__ A,
                                                 const ushort_t* __restrict__ Wt,
                                                 float* __restrict__ H, int M) {
    __shared__ __align__(16) ushort_t As[64 * 40];    // 5 KB
    __shared__ __align__(16) ushort_t Bs[128 * 40];   // 10 KB
    const int tid  = threadIdx.x;
    const int lane = tid & 63;
    const int wv   = tid >> 6;
    const int wy   = wv >> 1;          // 0..1 : row half
    const int wx   = wv & 1;           // 0..1 : col half
    const int row0 = blockIdx.x * 64;
    const int quad = lane >> 4;
    const int cl   = lane & 15;

    f32x4 acc[2][4] = {};

    // staging coords
    const int ar = tid >> 2, aq = tid & 3;            // A: row, 8-col group
    const int gr = min(row0 + ar, M - 1);
    const float*    aptr   = A + (size_t)gr * IN_FEAT + aq * 8;
    ushort_t*       as_dst = As + ar * 40 + aq * 8;
    const int br = tid >> 1, bh = tid & 1;            // B: n-row, 16-col half
    const ushort_t* wptr   = Wt + br * IN_FEAT + bh * 16;
    ushort_t*       bs_dst = Bs + br * 40 + bh * 16;

    for (int kc = 0; kc < IN_FEAT; kc += 32) {
        // load-before-barrier (global latency overlaps previous compute)
        float4 f0 = *(const float4*)(aptr + kc);
        float4 f1 = *(const float4*)(aptr + kc + 4);
        ushort8 w0 = *(const ushort8*)(wptr + kc);
        ushort8 w1 = *(const ushort8*)(wptr + kc + 8);
        ushort8 u;
        u[0] = f2bf(f0.x); u[1] = f2bf(f0.y); u[2] = f2bf(f0.z); u[3] = f2bf(f0.w);
        u[4] = f2bf(f1.x); u[5] = f2bf(f1.y); u[6] = f2bf(f1.z); u[7] = f2bf(f1.w);
        __syncthreads();                      // prior reads done before overwrite
        *(ushort8*)as_dst = u;
        *(ushort8*)bs_dst        = w0;
        *(ushort8*)(bs_dst + 8)  = w1;
        __syncthreads();

        bf16x8 af[2], bff[4];
#pragma unroll
        for (int mi = 0; mi < 2; ++mi)
            af[mi] = *(const bf16x8*)(As + (wy * 32 + mi * 16 + cl) * 40 + quad * 8);
#pragma unroll
        for (int ni = 0; ni < 4; ++ni)
            bff[ni] = *(const bf16x8*)(Bs + (wx * 64 + ni * 16 + cl) * 40 + quad * 8);
#pragma unroll
        for (int mi = 0; mi < 2; ++mi)
#pragma unroll
            for (int ni = 0; ni < 4; ++ni)
                acc[mi][ni] = __builtin_amdgcn_mfma_f32_16x16x32_bf16(
                    af[mi], bff[ni], acc[mi][ni], 0, 0, 0);
    }

    // epilogue: C layout col=lane&15, row=quad*4+reg
#pragma unroll
    for (int mi = 0; mi < 2; ++mi) {
#pragma unroll
        for (int ni = 0; ni < 4; ++ni) {
            int col = wx * 64 + ni * 16 + cl;
#pragma unroll
            for (int r = 0; r < 4; ++r) {
                int row = row0 + wy * 32 + mi * 16 + quad * 4 + r;
                if (row < M)
                    H[(size_t)row * UNITS + col] = acc[mi][ni][r];
            }
        }
    }
}

// ---------------------------------------------------------------------------
// K1b: per-node attention logits. One wave per node.
// ---------------------------------------------------------------------------
__global__ __launch_bounds__(256) void attn_dots(const float* __restrict__ H,
                                                 const float* __restrict__ ka,
                                                 float* __restrict__ a_tgt,
                                                 float* __restrict__ a_src, int M) {
    int wid  = (int)((blockIdx.x * 256 + threadIdx.x) >> 6);
    int lane = threadIdx.x & 63;
    if (wid >= M) return;
    float2 hv = *(const float2*)(H + (size_t)wid * UNITS + lane * 2);
    float2 kt = *(const float2*)(ka + lane * 2);
    float2 ks = *(const float2*)(ka + UNITS + lane * 2);
    float pt = hv.x * kt.x + hv.y * kt.y;
    float ps = hv.x * ks.x + hv.y * ks.y;
#pragma unroll
    for (int off = 32; off > 0; off >>= 1) {
        pt += __shfl_down(pt, off);
        ps += __shfl_down(ps, off);
    }
    if (lane == 0) { a_tgt[wid] = pt; a_src[wid] = ps; }
}

__device__ __forceinline__ float edge_score(float at, float as) {
    float s = at + as;
    s = s > 0.f ? s : 0.2f * s;          // leaky_relu
    s = fminf(fmaxf(s, -2.f), 2.f);      // clip
    return __expf(s);
}

// ---------------------------------------------------------------------------
// K2: per-edge score -> denom (fp32 atomic) + degree histogram (int atomic)
// ---------------------------------------------------------------------------
__global__ __launch_bounds__(256) void edge_scores(const int* __restrict__ edges,
                                                   const float* __restrict__ at,
                                                   const float* __restrict__ as,
                                                   float* __restrict__ denom,
                                                   int* __restrict__ counts, int E) {
    int e = blockIdx.x * 256 + threadIdx.x;
    if (e >= E) return;
    int2 ts = ((const int2*)edges)[e];   // (tgt, src)
    float sc = edge_score(at[ts.x], as[ts.y]);
    atomicAdd(&denom[ts.x], sc);
    atomicAdd(&counts[ts.x], 1);
}

// ---------------------------------------------------------------------------
// K3: single-block chunked scan, coalesced int4 loads. counts[0..n) -> offsets[0..n]
// ---------------------------------------------------------------------------
__global__ __launch_bounds__(1024) void scan_offsets(const int* __restrict__ counts,
                                                     int* __restrict__ offsets, int n) {
    __shared__ int wsum[16];
    __shared__ int total_sh;
    const int tid = threadIdx.x;
    const int lane = tid & 63, wid = tid >> 6;
    const int nch = (n + 4095) / 4096;
    int base = 0;

    for (int ch = 0; ch < nch; ++ch) {
        int i0 = ch * 4096 + tid * 4;
        int4 c = make_int4(0, 0, 0, 0);
        if (i0 + 3 < n) c = *(const int4*)(counts + i0);
        else if (i0 < n) {
            c.x = counts[i0];
            if (i0 + 1 < n) c.y = counts[i0 + 1];
            if (i0 + 2 < n) c.z = counts[i0 + 2];
        }
        int s = c.x + c.y + c.z + c.w;
        int incl = s;
#pragma unroll
        for (int off = 1; off < 64; off <<= 1) {
            int t = __shfl_up(incl, off);
            if (lane >= off) incl += t;
        }
        if (lane == 63) wsum[wid] = incl;
        __syncthreads();
        if (tid == 0) {
            int run = 0;
#pragma unroll
            for (int i = 0; i < 16; ++i) { int v = wsum[i]; wsum[i] = run; run += v; }
            total_sh = run;
        }
        __syncthreads();
        int excl = base + wsum[wid] + (incl - s);
        int4 o;
        o.x = excl; o.y = o.x + c.x; o.z = o.y + c.y; o.w = o.z + c.z;
        if (i0 + 3 < n) *(int4*)(offsets + i0) = o;
        else if (i0 < n) {
            offsets[i0] = o.x;
            if (i0 + 1 < n) offsets[i0 + 1] = o.y;
            if (i0 + 2 < n) offsets[i0 + 2] = o.z;
        }
        base += total_sh;
        __syncthreads();                 // protect wsum/total_sh for next chunk
    }
    if (tid == 0) offsets[n] = base;
}

// ---------------------------------------------------------------------------
// K4: scatter edges into CSR slots; store RAW score (divide deferred to K5)
// ---------------------------------------------------------------------------
__global__ __launch_bounds__(256) void build_csr(const int* __restrict__ edges,
                                                 const float* __restrict__ at,
                                                 const float* __restrict__ as,
                                                 const int* __restrict__ offsets,
                                                 int* __restrict__ cursor,
                                                 int* __restrict__ csr_src,
                                                 float* __restrict__ csr_w, int E) {
    int e = blockIdx.x * 256 + threadIdx.x;
    if (e >= E) return;
    int2 ts = ((const int2*)edges)[e];
    float sc = edge_score(at[ts.x], as[ts.y]);
    int pos = offsets[ts.x] + atomicAdd(&cursor[ts.x], 1);
    csr_src[pos] = ts.y;
    csr_w[pos]   = sc;
}

// ---------------------------------------------------------------------------
// K5: one wave per target node; lane covers 2 feature cols.
// Coalesced 512B gathers of h[src]; (src,w) broadcast via shfl; /denom at end.
// ---------------------------------------------------------------------------
__global__ __launch_bounds__(256) void aggregate(const float* __restrict__ H,
                                                 const int* __restrict__ offsets,
                                                 const int* __restrict__ csr_src,
                                                 const float* __restrict__ csr_w,
                                                 const float* __restrict__ denom,
                                                 float* __restrict__ out, int M) {
    int wid  = (int)((blockIdx.x * 256 + threadIdx.x) >> 6);
    int lane = threadIdx.x & 63;
    if (wid >= M) return;
    int beg = offsets[wid];
    int end = offsets[wid + 1];
    float2 acc = make_float2(0.f, 0.f);
    for (int base = beg; base < end; base += 64) {
        int cd = min(64, end - base);
        int s_v = 0; float w_v = 0.f;
        if (lane < cd) { s_v = csr_src[base + lane]; w_v = csr_w[base + lane]; }
        if (cd == 64) {
#pragma unroll 8
            for (int j = 0; j < 64; ++j) {
                int   src = __shfl(s_v, j);
                float w   = __shfl(w_v, j);
                float2 hv = *(const float2*)(H + (size_t)src * UNITS + lane * 2);
                acc.x += w * hv.x;
                acc.y += w * hv.y;
            }
        } else {
            for (int j = 0; j < cd; ++j) {
                int   src = __shfl(s_v, j);
                float w   = __shfl(w_v, j);
                float2 hv = *(const float2*)(H + (size_t)src * UNITS + lane * 2);
                acc.x += w * hv.x;
                acc.y += w * hv.y;
            }
        }
    }
    float scale = (end > beg) ? 1.0f / denom[wid] : 0.0f;
    acc.x *= scale; acc.y *= scale;
    *(float2*)(out + (size_t)wid * UNITS + lane * 2) = acc;
}

// ---------------------------------------------------------------------------
extern "C" void kernel_launch(void* const* d_in, const int* in_sizes, int n_in,
                              void* d_out, int out_size, void* d_ws, size_t ws_size,
                              hipStream_t stream) {
    const float* node_states = (const float*)d_in[0];
    const int*   edges       = (const int*)d_in[1];   // int32 pairs (tgt,src)
    const float* W           = (const float*)d_in[2];
    const float* ka          = (const float*)d_in[3];
    float*       out         = (float*)d_out;

    const int M = N_NODES, E = N_EDGES;

    // workspace layout (all 4B elems; no trailing backslashes in comments!)
    float* h       = (float*)d_ws;                     // M*128
    float* a_tgt   = h + (size_t)M * UNITS;            // M
    float* a_src   = a_tgt + M;                        // M
    float* denom   = a_src + M;                        // M  -- zeroed
    int*   counts  = (int*)(denom + M);                // M  -- zeroed
    int*   cursor  = counts + M;                       // M  -- zeroed
    int*   offsets = cursor + M;                       // M+1
    int*   csr_src = offsets + M + 1;                  // E
    float* csr_w   = (float*)(csr_src + E);            // E
    // Wt (64KB bf16) aliases csr_src: used only by prep_wt/gemm_mfma which
    // complete before build_csr writes csr_src. Stream-ordered => safe.
    ushort_t* wt   = (ushort_t*)csr_src;

    (void)hipMemsetAsync(denom, 0, (size_t)M * 3 * sizeof(int), stream);

    prep_wt     <<<(UNITS * IN_FEAT + 255) / 256, 256, 0, stream>>>(W, wt);
    gemm_mfma   <<<(M + 63) / 64, 256, 0, stream>>>(node_states, wt, h, M);
    attn_dots   <<<(M * 64 + 255) / 256, 256, 0, stream>>>(h, ka, a_tgt, a_src, M);
    edge_scores <<<(E + 255) / 256, 256, 0, stream>>>(edges, a_tgt, a_src, denom, counts, E);
    scan_offsets<<<1, 1024, 0, stream>>>(counts, offsets, M);
    build_csr   <<<(E + 255) / 256, 256, 0, stream>>>(edges, a_tgt, a_src, offsets,
                                                      cursor, csr_src, csr_w, E);
    aggregate   <<<(M * 64 + 255) / 256, 256, 0, stream>>>(h, offsets, csr_src, csr_w,
                                                           denom, out, M);
}

// Round 4
// 246.485 us; speedup vs baseline: 1.6959x; 1.3352x over previous
//
#include <hip/hip_runtime.h>
#include <hip/hip_bf16.h>

#define N_NODES 50000
#define N_EDGES 800000
#define IN_FEAT 256
#define UNITS   128

typedef unsigned short ushort_t;
typedef __bf16 bf16x8 __attribute__((ext_vector_type(8)));
typedef float  f32x4  __attribute__((ext_vector_type(4)));
typedef unsigned short ushort8 __attribute__((ext_vector_type(8)));

__device__ __forceinline__ ushort_t f2bf(float f) {
    unsigned u = __float_as_uint(f);
    u += 0x7fff + ((u >> 16) & 1);      // round-to-nearest-even
    return (ushort_t)(u >> 16);
}

// ---------------------------------------------------------------------------
// K0: Wt[n][k] = bf16(W[k][n])  (128 x 256 bf16, 64 KB) -- done once, tiny.
// ---------------------------------------------------------------------------
__global__ __launch_bounds__(256) void prep_wt(const float* __restrict__ W,
                                               ushort_t* __restrict__ Wt) {
    int i = blockIdx.x * 256 + threadIdx.x;     // i = n*256 + k
    if (i >= UNITS * IN_FEAT) return;
    int n = i >> 8;
    int k = i & 255;
    Wt[i] = f2bf(W[(size_t)k * UNITS + n]);
}

// ---------------------------------------------------------------------------
// K1: h(bf16) = A(50000x256 fp32 -> bf16) @ W via MFMA 16x16x32 bf16.
// BM=64, BN=128(full), BK=32. 256 thr = 4 waves in 2x2; wave tile 32x64.
// LDS row stride 40 bf16 (80B = 20 banks -> 2-way conflicts only, free).
// Output stored as bf16 to halve downstream gather traffic.
// ---------------------------------------------------------------------------
__global__ __launch_bounds__(256) void gemm_mfma(const float* __restrict__ A,
                                                 const ushort_t* __restrict__ Wt,
                                                 ushort_t* __restrict__ Hb, int M) {
    __shared__ __align__(16) ushort_t As[64 * 40];    // 5 KB
    __shared__ __align__(16) ushort_t Bs[128 * 40];   // 10 KB
    const int tid  = threadIdx.x;
    const int lane = tid & 63;
    const int wv   = tid >> 6;
    const int wy   = wv >> 1;          // 0..1 : row half
    const int wx   = wv & 1;           // 0..1 : col half
    const int row0 = blockIdx.x * 64;
    const int quad = lane >> 4;
    const int cl   = lane & 15;

    f32x4 acc[2][4] = {};

    // staging coords
    const int ar = tid >> 2, aq = tid & 3;            // A: row, 8-col group
    const int gr = min(row0 + ar, M - 1);
    const float*    aptr   = A + (size_t)gr * IN_FEAT + aq * 8;
    ushort_t*       as_dst = As + ar * 40 + aq * 8;
    const int br = tid >> 1, bh = tid & 1;            // B: n-row, 16-col half
    const ushort_t* wptr   = Wt + br * IN_FEAT + bh * 16;
    ushort_t*       bs_dst = Bs + br * 40 + bh * 16;

    for (int kc = 0; kc < IN_FEAT; kc += 32) {
        float4 f0 = *(const float4*)(aptr + kc);
        float4 f1 = *(const float4*)(aptr + kc + 4);
        ushort8 w0 = *(const ushort8*)(wptr + kc);
        ushort8 w1 = *(const ushort8*)(wptr + kc + 8);
        ushort8 u;
        u[0] = f2bf(f0.x); u[1] = f2bf(f0.y); u[2] = f2bf(f0.z); u[3] = f2bf(f0.w);
        u[4] = f2bf(f1.x); u[5] = f2bf(f1.y); u[6] = f2bf(f1.z); u[7] = f2bf(f1.w);
        __syncthreads();
        *(ushort8*)as_dst = u;
        *(ushort8*)bs_dst        = w0;
        *(ushort8*)(bs_dst + 8)  = w1;
        __syncthreads();

        bf16x8 af[2], bff[4];
#pragma unroll
        for (int mi = 0; mi < 2; ++mi)
            af[mi] = *(const bf16x8*)(As + (wy * 32 + mi * 16 + cl) * 40 + quad * 8);
#pragma unroll
        for (int ni = 0; ni < 4; ++ni)
            bff[ni] = *(const bf16x8*)(Bs + (wx * 64 + ni * 16 + cl) * 40 + quad * 8);
#pragma unroll
        for (int mi = 0; mi < 2; ++mi)
#pragma unroll
            for (int ni = 0; ni < 4; ++ni)
                acc[mi][ni] = __builtin_amdgcn_mfma_f32_16x16x32_bf16(
                    af[mi], bff[ni], acc[mi][ni], 0, 0, 0);
    }

    // epilogue: C layout col=lane&15, row=quad*4+reg; store bf16
#pragma unroll
    for (int mi = 0; mi < 2; ++mi) {
#pragma unroll
        for (int ni = 0; ni < 4; ++ni) {
            int col = wx * 64 + ni * 16 + cl;
#pragma unroll
            for (int r = 0; r < 4; ++r) {
                int row = row0 + wy * 32 + mi * 16 + quad * 4 + r;
                if (row < M)
                    Hb[(size_t)row * UNITS + col] = f2bf(acc[mi][ni][r]);
            }
        }
    }
}

// ---------------------------------------------------------------------------
// K1b: per-node attention logits from bf16 h. One wave per node.
// ---------------------------------------------------------------------------
__global__ __launch_bounds__(256) void attn_dots(const ushort_t* __restrict__ Hb,
                                                 const float* __restrict__ ka,
                                                 float* __restrict__ a_tgt,
                                                 float* __restrict__ a_src, int M) {
    int wid  = (int)((blockIdx.x * 256 + threadIdx.x) >> 6);
    int lane = threadIdx.x & 63;
    if (wid >= M) return;
    unsigned u = *(const unsigned*)(Hb + (size_t)wid * UNITS + lane * 2);
    float h0 = __uint_as_float(u << 16);
    float h1 = __uint_as_float(u & 0xffff0000u);
    float2 kt = *(const float2*)(ka + lane * 2);
    float2 ks = *(const float2*)(ka + UNITS + lane * 2);
    float pt = h0 * kt.x + h1 * kt.y;
    float ps = h0 * ks.x + h1 * ks.y;
#pragma unroll
    for (int off = 32; off > 0; off >>= 1) {
        pt += __shfl_down(pt, off);
        ps += __shfl_down(ps, off);
    }
    if (lane == 0) { a_tgt[wid] = pt; a_src[wid] = ps; }
}

__device__ __forceinline__ float edge_score(float at, float as) {
    float s = at + as;
    s = s > 0.f ? s : 0.2f * s;          // leaky_relu
    s = fminf(fmaxf(s, -2.f), 2.f);      // clip
    return __expf(s);
}

// ---------------------------------------------------------------------------
// K2: rank[e] = arrival index among edges with same tgt; counts histogram.
// ONE atomic per edge (was 3 across old K2+K4).
// ---------------------------------------------------------------------------
__global__ __launch_bounds__(256) void edge_rank(const int* __restrict__ edges,
                                                 int* __restrict__ counts,
                                                 int* __restrict__ rank_, int E) {
    int e = blockIdx.x * 256 + threadIdx.x;
    if (e >= E) return;
    int2 ts = ((const int2*)edges)[e];   // (tgt, src)
    rank_[e] = atomicAdd(&counts[ts.x], 1);
}

// ---------------------------------------------------------------------------
// K3: single-block chunked scan, coalesced int4 loads. counts[0..n) -> offsets[0..n]
// ---------------------------------------------------------------------------
__global__ __launch_bounds__(1024) void scan_offsets(const int* __restrict__ counts,
                                                     int* __restrict__ offsets, int n) {
    __shared__ int wsum[16];
    __shared__ int total_sh;
    const int tid = threadIdx.x;
    const int lane = tid & 63, wid = tid >> 6;
    const int nch = (n + 4095) / 4096;
    int base = 0;

    for (int ch = 0; ch < nch; ++ch) {
        int i0 = ch * 4096 + tid * 4;
        int4 c = make_int4(0, 0, 0, 0);
        if (i0 + 3 < n) c = *(const int4*)(counts + i0);
        else if (i0 < n) {
            c.x = counts[i0];
            if (i0 + 1 < n) c.y = counts[i0 + 1];
            if (i0 + 2 < n) c.z = counts[i0 + 2];
        }
        int s = c.x + c.y + c.z + c.w;
        int incl = s;
#pragma unroll
        for (int off = 1; off < 64; off <<= 1) {
            int t = __shfl_up(incl, off);
            if (lane >= off) incl += t;
        }
        if (lane == 63) wsum[wid] = incl;
        __syncthreads();
        if (tid == 0) {
            int run = 0;
#pragma unroll
            for (int i = 0; i < 16; ++i) { int v = wsum[i]; wsum[i] = run; run += v; }
            total_sh = run;
        }
        __syncthreads();
        int excl = base + wsum[wid] + (incl - s);
        int4 o;
        o.x = excl; o.y = o.x + c.x; o.z = o.y + c.y; o.w = o.z + c.z;
        if (i0 + 3 < n) *(int4*)(offsets + i0) = o;
        else if (i0 < n) {
            offsets[i0] = o.x;
            if (i0 + 1 < n) offsets[i0 + 1] = o.y;
            if (i0 + 2 < n) offsets[i0 + 2] = o.z;
        }
        base += total_sh;
        __syncthreads();
    }
    if (tid == 0) offsets[n] = base;
}

// ---------------------------------------------------------------------------
// K4: atomic-free CSR scatter; packed {src, score} int2 per entry.
// ---------------------------------------------------------------------------
__global__ __launch_bounds__(256) void build_csr(const int* __restrict__ edges,
                                                 const int* __restrict__ rank_,
                                                 const float* __restrict__ at,
                                                 const float* __restrict__ as,
                                                 const int* __restrict__ offsets,
                                                 int2* __restrict__ csr, int E) {
    int e = blockIdx.x * 256 + threadIdx.x;
    if (e >= E) return;
    int2 ts = ((const int2*)edges)[e];
    float sc = edge_score(at[ts.x], as[ts.y]);
    int pos = offsets[ts.x] + rank_[e];
    csr[pos] = make_int2(ts.y, __float_as_int(sc));
}

// ---------------------------------------------------------------------------
// K5: one wave per target node; lane covers 2 feature cols (4B bf16x2 gather).
// Denominator computed in-wave from raw scores (no denom array at all).
// ---------------------------------------------------------------------------
__global__ __launch_bounds__(256) void aggregate(const ushort_t* __restrict__ Hb,
                                                 const int* __restrict__ offsets,
                                                 const int2* __restrict__ csr,
                                                 float* __restrict__ out, int M) {
    int wid  = (int)((blockIdx.x * 256 + threadIdx.x) >> 6);
    int lane = threadIdx.x & 63;
    if (wid >= M) return;
    int beg = offsets[wid];
    int end = offsets[wid + 1];
    float2 acc = make_float2(0.f, 0.f);
    float wacc = 0.f;
    for (int base = beg; base < end; base += 64) {
        int cd = min(64, end - base);
        int s_v = 0; float w_v = 0.f;
        if (lane < cd) {
            int2 sw = csr[base + lane];
            s_v = sw.x;
            w_v = __int_as_float(sw.y);
        }
        wacc += w_v;
        if (cd == 64) {
#pragma unroll 8
            for (int j = 0; j < 64; ++j) {
                int   src = __shfl(s_v, j);
                float w   = __shfl(w_v, j);
                unsigned u = *(const unsigned*)(Hb + (size_t)src * UNITS + lane * 2);
                acc.x += w * __uint_as_float(u << 16);
                acc.y += w * __uint_as_float(u & 0xffff0000u);
            }
        } else {
            for (int j = 0; j < cd; ++j) {
                int   src = __shfl(s_v, j);
                float w   = __shfl(w_v, j);
                unsigned u = *(const unsigned*)(Hb + (size_t)src * UNITS + lane * 2);
                acc.x += w * __uint_as_float(u << 16);
                acc.y += w * __uint_as_float(u & 0xffff0000u);
            }
        }
    }
    // wave-reduce the raw-score sum -> denominator
#pragma unroll
    for (int off = 32; off > 0; off >>= 1) wacc += __shfl_down(wacc, off);
    float denom = __shfl(wacc, 0);
    float scale = (end > beg) ? 1.0f / denom : 0.0f;
    acc.x *= scale; acc.y *= scale;
    *(float2*)(out + (size_t)wid * UNITS + lane * 2) = acc;
}

// ---------------------------------------------------------------------------
extern "C" void kernel_launch(void* const* d_in, const int* in_sizes, int n_in,
                              void* d_out, int out_size, void* d_ws, size_t ws_size,
                              hipStream_t stream) {
    const float* node_states = (const float*)d_in[0];
    const int*   edges       = (const int*)d_in[1];   // int32 pairs (tgt,src)
    const float* W           = (const float*)d_in[2];
    const float* ka          = (const float*)d_in[3];
    float*       out         = (float*)d_out;

    const int M = N_NODES, E = N_EDGES;

    // workspace layout (no trailing backslashes in comments!)
    ushort_t* hb     = (ushort_t*)d_ws;                // M*128 bf16 = 12.8 MB
    float*    a_tgt  = (float*)(hb + (size_t)M * UNITS); // M
    float*    a_src  = a_tgt + M;                      // M
    int*      counts = (int*)(a_src + M);              // M  -- zeroed
    int*      offsets= counts + M;                     // M+2 (pad for int2 align)
    int*      rank_  = offsets + M + 2;                // E
    int2*     csr    = (int2*)(rank_ + E);             // E int2 (8B aligned)
    // Wt (64KB bf16) aliases csr storage: only used by prep_wt/gemm_mfma,
    // which complete before build_csr writes csr. Stream-ordered => safe.
    ushort_t* wt     = (ushort_t*)csr;

    (void)hipMemsetAsync(counts, 0, (size_t)M * sizeof(int), stream);

    prep_wt     <<<(UNITS * IN_FEAT + 255) / 256, 256, 0, stream>>>(W, wt);
    gemm_mfma   <<<(M + 63) / 64, 256, 0, stream>>>(node_states, wt, hb, M);
    attn_dots   <<<(M * 64 + 255) / 256, 256, 0, stream>>>(hb, ka, a_tgt, a_src, M);
    edge_rank   <<<(E + 255) / 256, 256, 0, stream>>>(edges, counts, rank_, E);
    scan_offsets<<<1, 1024, 0, stream>>>(counts, offsets, M);
    build_csr   <<<(E + 255) / 256, 256, 0, stream>>>(edges, rank_, a_tgt, a_src,
                                                      offsets, csr, E);
    aggregate   <<<(M * 64 + 255) / 256, 256, 0, stream>>>(hb, offsets, csr, out, M);
}

// Round 5
// 219.583 us; speedup vs baseline: 1.9036x; 1.1225x over previous
//
#include <hip/hip_runtime.h>
#include <hip/hip_bf16.h>

#define N_NODES 50000
#define N_EDGES 800000
#define IN_FEAT 256
#define UNITS   128

typedef unsigned short ushort_t;
typedef __bf16 bf16x8 __attribute__((ext_vector_type(8)));
typedef float  f32x4  __attribute__((ext_vector_type(4)));
typedef unsigned short ushort8 __attribute__((ext_vector_type(8)));

__device__ __forceinline__ ushort_t f2bf(float f) {
    unsigned u = __float_as_uint(f);
    u += 0x7fff + ((u >> 16) & 1);      // round-to-nearest-even
    return (ushort_t)(u >> 16);
}

// ---------------------------------------------------------------------------
// K0: Wt[n][k] = bf16(W[k][n])  (128 x 256 bf16, 64 KB) -- done once, tiny.
// ---------------------------------------------------------------------------
__global__ __launch_bounds__(256) void prep_wt(const float* __restrict__ W,
                                               ushort_t* __restrict__ Wt) {
    int i = blockIdx.x * 256 + threadIdx.x;     // i = n*256 + k
    if (i >= UNITS * IN_FEAT) return;
    int n = i >> 8;
    int k = i & 255;
    Wt[i] = f2bf(W[(size_t)k * UNITS + n]);
}

// ---------------------------------------------------------------------------
// K1: h(bf16) = A(50000x256 fp32 -> bf16) @ W via MFMA 16x16x32 bf16.
// BM=64, BN=128(full), BK=32. 256 thr = 4 waves in 2x2; wave tile 32x64.
// LDS row stride 40 bf16 (80B = 20 banks -> 2-way conflicts only, free).
// ---------------------------------------------------------------------------
__global__ __launch_bounds__(256) void gemm_mfma(const float* __restrict__ A,
                                                 const ushort_t* __restrict__ Wt,
                                                 ushort_t* __restrict__ Hb, int M) {
    __shared__ __align__(16) ushort_t As[64 * 40];    // 5 KB
    __shared__ __align__(16) ushort_t Bs[128 * 40];   // 10 KB
    const int tid  = threadIdx.x;
    const int lane = tid & 63;
    const int wv   = tid >> 6;
    const int wy   = wv >> 1;          // 0..1 : row half
    const int wx   = wv & 1;           // 0..1 : col half
    const int row0 = blockIdx.x * 64;
    const int quad = lane >> 4;
    const int cl   = lane & 15;

    f32x4 acc[2][4] = {};

    const int ar = tid >> 2, aq = tid & 3;            // A: row, 8-col group
    const int gr = min(row0 + ar, M - 1);
    const float*    aptr   = A + (size_t)gr * IN_FEAT + aq * 8;
    ushort_t*       as_dst = As + ar * 40 + aq * 8;
    const int br = tid >> 1, bh = tid & 1;            // B: n-row, 16-col half
    const ushort_t* wptr   = Wt + br * IN_FEAT + bh * 16;
    ushort_t*       bs_dst = Bs + br * 40 + bh * 16;

    for (int kc = 0; kc < IN_FEAT; kc += 32) {
        float4 f0 = *(const float4*)(aptr + kc);
        float4 f1 = *(const float4*)(aptr + kc + 4);
        ushort8 w0 = *(const ushort8*)(wptr + kc);
        ushort8 w1 = *(const ushort8*)(wptr + kc + 8);
        ushort8 u;
        u[0] = f2bf(f0.x); u[1] = f2bf(f0.y); u[2] = f2bf(f0.z); u[3] = f2bf(f0.w);
        u[4] = f2bf(f1.x); u[5] = f2bf(f1.y); u[6] = f2bf(f1.z); u[7] = f2bf(f1.w);
        __syncthreads();
        *(ushort8*)as_dst = u;
        *(ushort8*)bs_dst        = w0;
        *(ushort8*)(bs_dst + 8)  = w1;
        __syncthreads();

        bf16x8 af[2], bff[4];
#pragma unroll
        for (int mi = 0; mi < 2; ++mi)
            af[mi] = *(const bf16x8*)(As + (wy * 32 + mi * 16 + cl) * 40 + quad * 8);
#pragma unroll
        for (int ni = 0; ni < 4; ++ni)
            bff[ni] = *(const bf16x8*)(Bs + (wx * 64 + ni * 16 + cl) * 40 + quad * 8);
#pragma unroll
        for (int mi = 0; mi < 2; ++mi)
#pragma unroll
            for (int ni = 0; ni < 4; ++ni)
                acc[mi][ni] = __builtin_amdgcn_mfma_f32_16x16x32_bf16(
                    af[mi], bff[ni], acc[mi][ni], 0, 0, 0);
    }

#pragma unroll
    for (int mi = 0; mi < 2; ++mi) {
#pragma unroll
        for (int ni = 0; ni < 4; ++ni) {
            int col = wx * 64 + ni * 16 + cl;
#pragma unroll
            for (int r = 0; r < 4; ++r) {
                int row = row0 + wy * 32 + mi * 16 + quad * 4 + r;
                if (row < M)
                    Hb[(size_t)row * UNITS + col] = f2bf(acc[mi][ni][r]);
            }
        }
    }
}

// ---------------------------------------------------------------------------
// K1b: per-node attention logits from bf16 h. One wave per node.
// ---------------------------------------------------------------------------
__global__ __launch_bounds__(256) void attn_dots(const ushort_t* __restrict__ Hb,
                                                 const float* __restrict__ ka,
                                                 float* __restrict__ a_tgt,
                                                 float* __restrict__ a_src, int M) {
    int wid  = (int)((blockIdx.x * 256 + threadIdx.x) >> 6);
    int lane = threadIdx.x & 63;
    if (wid >= M) return;
    unsigned u = *(const unsigned*)(Hb + (size_t)wid * UNITS + lane * 2);
    float h0 = __uint_as_float(u << 16);
    float h1 = __uint_as_float(u & 0xffff0000u);
    float2 kt = *(const float2*)(ka + lane * 2);
    float2 ks = *(const float2*)(ka + UNITS + lane * 2);
    float pt = h0 * kt.x + h1 * kt.y;
    float ps = h0 * ks.x + h1 * ks.y;
#pragma unroll
    for (int off = 32; off > 0; off >>= 1) {
        pt += __shfl_down(pt, off);
        ps += __shfl_down(ps, off);
    }
    if (lane == 0) { a_tgt[wid] = pt; a_src[wid] = ps; }
}

__device__ __forceinline__ float edge_score(float at, float as) {
    float s = at + as;
    s = s > 0.f ? s : 0.2f * s;          // leaky_relu
    s = fminf(fmaxf(s, -2.f), 2.f);      // clip
    return __expf(s);
}

// ---------------------------------------------------------------------------
// K2: rank[e] = arrival index among edges with same tgt; counts histogram.
// ---------------------------------------------------------------------------
__global__ __launch_bounds__(256) void edge_rank(const int* __restrict__ edges,
                                                 int* __restrict__ counts,
                                                 int* __restrict__ rank_, int E) {
    int e = blockIdx.x * 256 + threadIdx.x;
    if (e >= E) return;
    int2 ts = ((const int2*)edges)[e];   // (tgt, src)
    rank_[e] = atomicAdd(&counts[ts.x], 1);
}

// ---------------------------------------------------------------------------
// K3: single-block chunked scan, coalesced int4 loads. counts[0..n) -> offsets[0..n]
// ---------------------------------------------------------------------------
__global__ __launch_bounds__(1024) void scan_offsets(const int* __restrict__ counts,
                                                     int* __restrict__ offsets, int n) {
    __shared__ int wsum[16];
    __shared__ int total_sh;
    const int tid = threadIdx.x;
    const int lane = tid & 63, wid = tid >> 6;
    const int nch = (n + 4095) / 4096;
    int base = 0;

    for (int ch = 0; ch < nch; ++ch) {
        int i0 = ch * 4096 + tid * 4;
        int4 c = make_int4(0, 0, 0, 0);
        if (i0 + 3 < n) c = *(const int4*)(counts + i0);
        else if (i0 < n) {
            c.x = counts[i0];
            if (i0 + 1 < n) c.y = counts[i0 + 1];
            if (i0 + 2 < n) c.z = counts[i0 + 2];
        }
        int s = c.x + c.y + c.z + c.w;
        int incl = s;
#pragma unroll
        for (int off = 1; off < 64; off <<= 1) {
            int t = __shfl_up(incl, off);
            if (lane >= off) incl += t;
        }
        if (lane == 63) wsum[wid] = incl;
        __syncthreads();
        if (tid == 0) {
            int run = 0;
#pragma unroll
            for (int i = 0; i < 16; ++i) { int v = wsum[i]; wsum[i] = run; run += v; }
            total_sh = run;
        }
        __syncthreads();
        int excl = base + wsum[wid] + (incl - s);
        int4 o;
        o.x = excl; o.y = o.x + c.x; o.z = o.y + c.y; o.w = o.z + c.z;
        if (i0 + 3 < n) *(int4*)(offsets + i0) = o;
        else if (i0 < n) {
            offsets[i0] = o.x;
            if (i0 + 1 < n) offsets[i0 + 1] = o.y;
            if (i0 + 2 < n) offsets[i0 + 2] = o.z;
        }
        base += total_sh;
        __syncthreads();
    }
    if (tid == 0) offsets[n] = base;
}

// ---------------------------------------------------------------------------
// K4: atomic-free CSR scatter; packed {src, score} int2 per entry.
// ---------------------------------------------------------------------------
__global__ __launch_bounds__(256) void build_csr(const int* __restrict__ edges,
                                                 const int* __restrict__ rank_,
                                                 const float* __restrict__ at,
                                                 const float* __restrict__ as,
                                                 const int* __restrict__ offsets,
                                                 int2* __restrict__ csr, int E) {
    int e = blockIdx.x * 256 + threadIdx.x;
    if (e >= E) return;
    int2 ts = ((const int2*)edges)[e];
    float sc = edge_score(at[ts.x], as[ts.y]);
    int pos = offsets[ts.x] + rank_[e];
    csr[pos] = make_int2(ts.y, __float_as_int(sc));
}

// ---------------------------------------------------------------------------
// K5: one wave per target node; 4 edge-slots x 16 feature-lanes.
// Lane g*16+c loads 16B (8 bf16) of h[src_g] -> one dwordx4 instruction
// covers 4 independent rows => ~4x shorter exposed-latency chain than the
// old 1-row-per-step scheme (mean degree 16 -> 4 steps).
// ---------------------------------------------------------------------------
__global__ __launch_bounds__(256) void aggregate(const ushort_t* __restrict__ Hb,
                                                 const int* __restrict__ offsets,
                                                 const int2* __restrict__ csr,
                                                 float* __restrict__ out, int M) {
    int wid  = (int)((blockIdx.x * 256 + threadIdx.x) >> 6);
    int lane = threadIdx.x & 63;
    if (wid >= M) return;
    const int g = lane >> 4;            // edge slot 0..3
    const int c = lane & 15;            // feature chunk: feats [c*8, c*8+8)
    int beg = offsets[wid];
    int end = offsets[wid + 1];

    float acc[8] = {};
    float wacc = 0.f;

    for (int base = beg; base < end; base += 64) {
        int cd = min(64, end - base);
        int   s_v = 0;
        float w_v = 0.f;
        if (lane < cd) {
            int2 sw = csr[base + lane];
            s_v = sw.x;
            w_v = __int_as_float(sw.y);
        }
        wacc += w_v;                     // raw-score partial sum (whole wave)
        int nstep = (cd + 3) >> 2;
#pragma unroll 4
        for (int t = 0; t < nstep; ++t) {
            int slot = t * 4 + g;        // inactive slots: w=0, src=0 (safe)
            int   src = __shfl(s_v, slot);
            float w   = __shfl(w_v, slot);
            uint4 u = *(const uint4*)(Hb + (size_t)src * UNITS + c * 8);
            acc[0] += w * __uint_as_float(u.x << 16);
            acc[1] += w * __uint_as_float(u.x & 0xffff0000u);
            acc[2] += w * __uint_as_float(u.y << 16);
            acc[3] += w * __uint_as_float(u.y & 0xffff0000u);
            acc[4] += w * __uint_as_float(u.z << 16);
            acc[5] += w * __uint_as_float(u.z & 0xffff0000u);
            acc[6] += w * __uint_as_float(u.w << 16);
            acc[7] += w * __uint_as_float(u.w & 0xffff0000u);
        }
    }

    // combine the 4 edge-slot partials (lanes c, c+16, c+32, c+48)
#pragma unroll
    for (int i = 0; i < 8; ++i) {
        acc[i] += __shfl_xor(acc[i], 16);
        acc[i] += __shfl_xor(acc[i], 32);
    }
    // full-wave reduce of the raw-score sum -> denominator
#pragma unroll
    for (int off = 32; off > 0; off >>= 1) wacc += __shfl_xor(wacc, off);
    float scale = (end > beg) ? 1.0f / wacc : 0.0f;

    if (g == 0) {                        // 16 lanes x 32B = contiguous 512B
        float4 o0 = make_float4(acc[0] * scale, acc[1] * scale,
                                acc[2] * scale, acc[3] * scale);
        float4 o1 = make_float4(acc[4] * scale, acc[5] * scale,
                                acc[6] * scale, acc[7] * scale);
        float* dst = out + (size_t)wid * UNITS + c * 8;
        *(float4*)dst       = o0;
        *(float4*)(dst + 4) = o1;
    }
}

// ---------------------------------------------------------------------------
extern "C" void kernel_launch(void* const* d_in, const int* in_sizes, int n_in,
                              void* d_out, int out_size, void* d_ws, size_t ws_size,
                              hipStream_t stream) {
    const float* node_states = (const float*)d_in[0];
    const int*   edges       = (const int*)d_in[1];   // int32 pairs (tgt,src)
    const float* W           = (const float*)d_in[2];
    const float* ka          = (const float*)d_in[3];
    float*       out         = (float*)d_out;

    const int M = N_NODES, E = N_EDGES;

    // workspace layout (no trailing backslashes in comments!)
    ushort_t* hb     = (ushort_t*)d_ws;                // M*128 bf16 = 12.8 MB
    float*    a_tgt  = (float*)(hb + (size_t)M * UNITS); // M
    float*    a_src  = a_tgt + M;                      // M
    int*      counts = (int*)(a_src + M);              // M  -- zeroed
    int*      offsets= counts + M;                     // M+2 (pad for int2 align)
    int*      rank_  = offsets + M + 2;                // E
    int2*     csr    = (int2*)(rank_ + E);             // E int2 (8B aligned)
    // Wt (64KB bf16) aliases csr storage: only used by prep_wt/gemm_mfma,
    // which complete before build_csr writes csr. Stream-ordered => safe.
    ushort_t* wt     = (ushort_t*)csr;

    (void)hipMemsetAsync(counts, 0, (size_t)M * sizeof(int), stream);

    prep_wt     <<<(UNITS * IN_FEAT + 255) / 256, 256, 0, stream>>>(W, wt);
    gemm_mfma   <<<(M + 63) / 64, 256, 0, stream>>>(node_states, wt, hb, M);
    attn_dots   <<<(M * 64 + 255) / 256, 256, 0, stream>>>(hb, ka, a_tgt, a_src, M);
    edge_rank   <<<(E + 255) / 256, 256, 0, stream>>>(edges, counts, rank_, E);
    scan_offsets<<<1, 1024, 0, stream>>>(counts, offsets, M);
    build_csr   <<<(E + 255) / 256, 256, 0, stream>>>(edges, rank_, a_tgt, a_src,
                                                      offsets, csr, E);
    aggregate   <<<(M * 64 + 255) / 256, 256, 0, stream>>>(hb, offsets, csr, out, M);
}